// Round 8
// baseline (632.216 us; speedup 1.0000x reference)
//
#include <hip/hip_runtime.h>
#include <hip/hip_bf16.h>

#define N_NODES 50000
#define DIM 128
#define N_GRAPHS 64
#define E_RAW 800000
#define E_TOT 850000
#define E_CAP 1200000   // >= E_TOT + 3*N_NODES (pad-to-4) + slack
#define NEG_SLOPE 0.2f

typedef unsigned int uint;
typedef unsigned short ushort;
typedef float v2f __attribute__((ext_vector_type(2)));

// ---------- init ----------
__global__ void init_kernel(int* deg, int* fillc, float* pooled, int* csr_src) {
    int i = blockIdx.x * blockDim.x + threadIdx.x;
    if (i < N_NODES) { deg[i] = 0; fillc[i] = 0; }
    if (i < N_GRAPHS * DIM) pooled[i] = 0.f;
    if (i < E_CAP) csr_src[i] = -1;
}

// ---------- CSR build (dst-sorted, segments padded to multiple of 4) ----------
__global__ void count_kernel(const int* __restrict__ ei, int* __restrict__ deg) {
    int e = blockIdx.x * blockDim.x + threadIdx.x;
    if (e >= E_TOT) return;
    int dst = (e < E_RAW) ? ei[E_RAW + e] : (e - E_RAW);
    atomicAdd(&deg[dst], 1);
}

__global__ void scan1_kernel(const int* __restrict__ deg, int* __restrict__ excl,
                             int* __restrict__ blksum, int n) {
    __shared__ int lds[256];
    int t = threadIdx.x;
    int i = blockIdx.x * 256 + t;
    int v = (i < n) ? ((deg[i] + 3) & ~3) : 0;   // pad degree to multiple of 4
    lds[t] = v;
    __syncthreads();
    int incl = v;
    for (int off = 1; off < 256; off <<= 1) {
        int y = (t >= off) ? lds[t - off] : 0;
        __syncthreads();
        incl += y;
        lds[t] = incl;
        __syncthreads();
    }
    if (i < n) excl[i] = incl - v;
    if (t == 255) blksum[blockIdx.x] = incl;
}

__global__ void scan2_kernel(int* __restrict__ blksum, int* __restrict__ row_ptr, int nblk) {
    __shared__ int lds[256];
    int t = threadIdx.x;
    int v = (t < nblk) ? blksum[t] : 0;
    lds[t] = v;
    __syncthreads();
    int incl = v;
    for (int off = 1; off < 256; off <<= 1) {
        int y = (t >= off) ? lds[t - off] : 0;
        __syncthreads();
        incl += y;
        lds[t] = incl;
        __syncthreads();
    }
    if (t < nblk) blksum[t] = incl - v;
    if (t == nblk - 1) row_ptr[N_NODES] = incl;
}

__global__ void scan3_kernel(int* __restrict__ row_ptr, const int* __restrict__ blksum, int n) {
    int i = blockIdx.x * blockDim.x + threadIdx.x;
    if (i < n) row_ptr[i] += blksum[i >> 8];
}

__global__ void fill_kernel(const int* __restrict__ ei, const int* __restrict__ row_ptr,
                            int* __restrict__ fillc, int* __restrict__ csr_src) {
    int e = blockIdx.x * blockDim.x + threadIdx.x;
    if (e >= E_TOT) return;
    int src, dst;
    if (e < E_RAW) { src = ei[e]; dst = ei[E_RAW + e]; }
    else           { src = dst = e - E_RAW; }
    int slot = row_ptr[dst] + atomicAdd(&fillc[dst], 1);
    csr_src[slot] = src;
}

// ---------- GEMM + fused attention dots; H written as packed fp8 e4m3 ----------
__global__ __launch_bounds__(256) void gemm_dots_kernel(
    const float* __restrict__ X, const float* __restrict__ W,
    const float* __restrict__ asrc, const float* __restrict__ adst,
    uint* __restrict__ Hb, float* __restrict__ s1, float* __restrict__ s2, int nrows) {
    __shared__ float Wl[DIM][DIM];
    int t = threadIdx.x;
    for (int i = t; i < DIM * DIM / 4; i += 256)
        ((float4*)&Wl[0][0])[i] = ((const float4*)W)[i];
    __syncthreads();

    int tx = t & 15, ty = t >> 4;
    int row0 = blockIdx.x * 128 + ty * 8;
    int col0 = tx * 8;
    float acc[8][8];
#pragma unroll
    for (int r = 0; r < 8; ++r)
#pragma unroll
        for (int c = 0; c < 8; ++c) acc[r][c] = 0.f;

    for (int k = 0; k < DIM; k += 4) {
        float4 xr[8];
#pragma unroll
        for (int r = 0; r < 8; ++r) {
            int row = row0 + r;
            xr[r] = (row < nrows) ? *(const float4*)&X[row * DIM + k]
                                  : make_float4(0.f, 0.f, 0.f, 0.f);
        }
#pragma unroll
        for (int kk = 0; kk < 4; ++kk) {
            float w0[8];
#pragma unroll
            for (int c = 0; c < 8; ++c) w0[c] = Wl[k + kk][col0 + c];
#pragma unroll
            for (int r = 0; r < 8; ++r) {
                float xv = (kk == 0) ? xr[r].x : (kk == 1) ? xr[r].y : (kk == 2) ? xr[r].z : xr[r].w;
#pragma unroll
                for (int c = 0; c < 8; ++c) acc[r][c] = fmaf(xv, w0[c], acc[r][c]);
            }
        }
    }

    float a1r[8], a2r[8];
#pragma unroll
    for (int c = 0; c < 8; ++c) { a1r[c] = asrc[col0 + c]; a2r[c] = adst[col0 + c]; }

#pragma unroll
    for (int r = 0; r < 8; ++r) {
        int row = row0 + r;
        if (row < nrows) {
            int w0 = __builtin_amdgcn_cvt_pk_fp8_f32(acc[r][0], acc[r][1], 0, false);
            w0     = __builtin_amdgcn_cvt_pk_fp8_f32(acc[r][2], acc[r][3], w0, true);
            int w1 = __builtin_amdgcn_cvt_pk_fp8_f32(acc[r][4], acc[r][5], 0, false);
            w1     = __builtin_amdgcn_cvt_pk_fp8_f32(acc[r][6], acc[r][7], w1, true);
            *(uint2*)&Hb[(size_t)row * 32 + tx * 2] = make_uint2((uint)w0, (uint)w1);
        }
        float p1 = 0.f, p2 = 0.f;
#pragma unroll
        for (int c = 0; c < 8; ++c) { p1 = fmaf(acc[r][c], a1r[c], p1); p2 = fmaf(acc[r][c], a2r[c], p2); }
#pragma unroll
        for (int m = 1; m < 16; m <<= 1) { p1 += __shfl_xor(p1, m); p2 += __shfl_xor(p2, m); }
        if (tx == 0 && row < nrows) { s1[row] = p1; s2[row] = p2; }
    }
}

// ---------- fused softmax + aggregation: HALF-wave (32 lanes) per dst node ----------
// Each gather instruction serves 2 edges (one per half; 2 address segments).
// Lane owns 4 dims (uint = 4 fp8). Segments padded to multiple of 4; the second
// quad of each 8-edge step is masked if it crosses the segment end.
__global__ __launch_bounds__(256) void agg_kernel(
    const uint* __restrict__ Hb32, const int* __restrict__ csr_src,
    const int* __restrict__ row_ptr, const float* __restrict__ s1,
    const float* __restrict__ s2n, const float* __restrict__ bias,
    float4* __restrict__ Xout4, const int* __restrict__ batch,
    float* __restrict__ pooled, int pool_flag, int npairs) {
    int gw = (blockIdx.x * blockDim.x + threadIdx.x) >> 6;
    int lane = threadIdx.x & 63;
    if (gw >= npairs) return;
    int sub = lane & 31;
    int node = 2 * gw + (lane >> 5);     // N_NODES even -> always valid
    int beg = row_ptr[node], end = row_ptr[node + 1];
    float s2v = s2n[node];
    float4 acc = make_float4(0.f, 0.f, 0.f, 0.f);
    float wsum = 0.f;

    for (int s = beg; s < end; s += 8) {
        int4 a = *(const int4*)&csr_src[s];       // always within this segment (pad-to-4)
        int4 b = *(const int4*)&csr_src[s + 4];   // may overrun into next segment
        bool vb = (s + 4) < end;
        int sn[8];
        sn[0] = a.x; sn[1] = a.y; sn[2] = a.z; sn[3] = a.w;
        sn[4] = vb ? b.x : -1; sn[5] = vb ? b.y : -1;
        sn[6] = vb ? b.z : -1; sn[7] = vb ? b.w : -1;

        uint hv[8];
#pragma unroll
        for (int j = 0; j < 8; ++j) {
            int r = (sn[j] < 0) ? 0 : sn[j];
            hv[j] = Hb32[(size_t)r * 32 + sub];
        }
        float w[8];
#pragma unroll
        for (int j = 0; j < 8; ++j) {
            int r = (sn[j] < 0) ? 0 : sn[j];
            float al = s1[r] + s2v;
            al = (al > 0.f) ? al : NEG_SLOPE * al;
            float e = __expf(al);
            w[j] = (sn[j] < 0) ? 0.f : e;
            wsum += w[j];
        }
#pragma unroll
        for (int j = 0; j < 8; ++j) {
            v2f lo = __builtin_amdgcn_cvt_pk_f32_fp8((int)hv[j], false);
            v2f hi = __builtin_amdgcn_cvt_pk_f32_fp8((int)hv[j], true);
            acc.x = fmaf(w[j], lo.x, acc.x);
            acc.y = fmaf(w[j], lo.y, acc.y);
            acc.z = fmaf(w[j], hi.x, acc.z);
            acc.w = fmaf(w[j], hi.y, acc.w);
        }
    }

    float inv = 1.f / (wsum + 1e-16f);
    float4 b4 = ((const float4*)bias)[sub];
    acc.x = fmaxf(fmaf(acc.x, inv, b4.x), 0.f);
    acc.y = fmaxf(fmaf(acc.y, inv, b4.y), 0.f);
    acc.z = fmaxf(fmaf(acc.z, inv, b4.z), 0.f);
    acc.w = fmaxf(fmaf(acc.w, inv, b4.w), 0.f);
    Xout4[(size_t)node * 32 + sub] = acc;   // 2 halves -> contiguous 1 KiB per wave
    if (pool_flag) {
        int g = batch[node];
        atomicAdd(&pooled[g * DIM + sub * 4 + 0], acc.x);
        atomicAdd(&pooled[g * DIM + sub * 4 + 1], acc.y);
        atomicAdd(&pooled[g * DIM + sub * 4 + 2], acc.z);
        atomicAdd(&pooled[g * DIM + sub * 4 + 3], acc.w);
    }
}

__global__ void final_kernel(const float* __restrict__ pooled, const float* __restrict__ Wf,
                             const float* __restrict__ bf, float* __restrict__ y) {
    int wid = (blockIdx.x * blockDim.x + threadIdx.x) >> 6;
    int lane = threadIdx.x & 63;
    if (wid >= N_GRAPHS) return;
    float2 p = *(const float2*)&pooled[wid * DIM + 2 * lane];
    float2 w = *(const float2*)&Wf[2 * lane];
    float v = p.x * w.x + p.y * w.y;
    for (int off = 32; off; off >>= 1) v += __shfl_down(v, off);
    if (lane == 0) y[wid] = v + bf[0];
}

extern "C" void kernel_launch(void* const* d_in, const int* in_sizes, int n_in,
                              void* d_out, int out_size, void* d_ws, size_t ws_size,
                              hipStream_t stream) {
    const float* x       = (const float*)d_in[0];
    const int*   ei      = (const int*)d_in[1];
    const int*   batch   = (const int*)d_in[2];
    const float* Ws      = (const float*)d_in[3];
    const float* att_src = (const float*)d_in[4];
    const float* att_dst = (const float*)d_in[5];
    const float* biases  = (const float*)d_in[6];
    const float* Wf      = (const float*)d_in[7];
    const float* bf      = (const float*)d_in[8];
    float* y = (float*)d_out;

    char* p = (char*)d_ws;
    auto alloc = [&](size_t bytes) -> void* {
        void* r = (void*)p;
        p += (bytes + 255) & ~(size_t)255;
        return r;
    };
    float* xA      = (float*)alloc((size_t)N_NODES * DIM * 4);
    float* xB      = (float*)alloc((size_t)N_NODES * DIM * 4);
    uint*  Hb      = (uint*)alloc((size_t)N_NODES * 32 * 4);   // fp8 e4m3, 128 B/row
    int*   csr_src = (int*)alloc((size_t)E_CAP * 4);
    int*   deg     = (int*)alloc((size_t)N_NODES * 4);
    int*   fillc   = (int*)alloc((size_t)N_NODES * 4);
    int*   row_ptr = (int*)alloc((size_t)(N_NODES + 1) * 4);
    int*   blksum  = (int*)alloc(256 * 4);
    float* s1      = (float*)alloc((size_t)N_NODES * 4);
    float* s2      = (float*)alloc((size_t)N_NODES * 4);
    float* pooled  = (float*)alloc((size_t)N_GRAPHS * DIM * 4);

    const int BN = 256;
    const int gN    = (N_NODES + BN - 1) / BN;
    const int gE    = (E_TOT + BN - 1) / BN;
    const int gI    = (E_CAP + BN - 1) / BN;
    const int npairs = N_NODES / 2;
    const int gAGG  = (npairs * 64 + BN - 1) / BN;   // one wave per node-PAIR
    const int nblk  = gN;

    init_kernel<<<gI, BN, 0, stream>>>(deg, fillc, pooled, csr_src);
    count_kernel<<<gE, BN, 0, stream>>>(ei, deg);
    scan1_kernel<<<nblk, BN, 0, stream>>>(deg, row_ptr, blksum, N_NODES);
    scan2_kernel<<<1, BN, 0, stream>>>(blksum, row_ptr, nblk);
    scan3_kernel<<<gN, BN, 0, stream>>>(row_ptr, blksum, N_NODES);
    fill_kernel<<<gE, BN, 0, stream>>>(ei, row_ptr, fillc, csr_src);

    const float* xin = x;
    float* xout = xA;
    for (int l = 0; l < 3; ++l) {
        const float* W  = Ws + (size_t)l * DIM * DIM;
        const float* as = att_src + (size_t)l * DIM;
        const float* ad = att_dst + (size_t)l * DIM;
        const float* b  = biases + (size_t)l * DIM;

        gemm_dots_kernel<<<(N_NODES + 127) / 128, BN, 0, stream>>>(xin, W, as, ad, Hb, s1, s2, N_NODES);
        agg_kernel<<<gAGG, BN, 0, stream>>>(Hb, csr_src, row_ptr, s1, s2, b,
                                            (float4*)xout, batch, pooled,
                                            (l == 2) ? 1 : 0, npairs);
        xin = xout;
        xout = (l == 0) ? xB : xA;
    }

    final_kernel<<<(N_GRAPHS * 64 + BN - 1) / BN, BN, 0, stream>>>(pooled, Wf, bf, y);
    (void)ws_size; (void)n_in; (void)in_sizes; (void)out_size;
}

// Round 9
// 566.631 us; speedup vs baseline: 1.1157x; 1.1157x over previous
//
#include <hip/hip_runtime.h>
#include <hip/hip_bf16.h>

#define N_NODES 50000
#define DIM 128
#define N_GRAPHS 64
#define E_RAW 800000
#define E_TOT 850000
#define E_CAP 1200000   // >= E_TOT + 3*N_NODES (pad-to-4) + slack
#define NEG_SLOPE 0.2f

typedef unsigned int uint;
typedef unsigned short ushort;
typedef float v2f __attribute__((ext_vector_type(2)));

// ---------- init ----------
__global__ void init_kernel(int* deg, int* fillc, float* pooled, int* csr_src) {
    int i = blockIdx.x * blockDim.x + threadIdx.x;
    if (i < N_NODES) { deg[i] = 0; fillc[i] = 0; }
    if (i < N_GRAPHS * DIM) pooled[i] = 0.f;
    if (i < E_CAP) csr_src[i] = -1;
}

// ---------- CSR build (dst-sorted, segments padded to multiple of 4) ----------
__global__ void count_kernel(const int* __restrict__ ei, int* __restrict__ deg) {
    int e = blockIdx.x * blockDim.x + threadIdx.x;
    if (e >= E_TOT) return;
    int dst = (e < E_RAW) ? ei[E_RAW + e] : (e - E_RAW);
    atomicAdd(&deg[dst], 1);
}

__global__ void scan1_kernel(const int* __restrict__ deg, int* __restrict__ excl,
                             int* __restrict__ blksum, int n) {
    __shared__ int lds[256];
    int t = threadIdx.x;
    int i = blockIdx.x * 256 + t;
    int v = (i < n) ? ((deg[i] + 3) & ~3) : 0;   // pad degree to multiple of 4
    lds[t] = v;
    __syncthreads();
    int incl = v;
    for (int off = 1; off < 256; off <<= 1) {
        int y = (t >= off) ? lds[t - off] : 0;
        __syncthreads();
        incl += y;
        lds[t] = incl;
        __syncthreads();
    }
    if (i < n) excl[i] = incl - v;
    if (t == 255) blksum[blockIdx.x] = incl;
}

__global__ void scan2_kernel(int* __restrict__ blksum, int* __restrict__ row_ptr, int nblk) {
    __shared__ int lds[256];
    int t = threadIdx.x;
    int v = (t < nblk) ? blksum[t] : 0;
    lds[t] = v;
    __syncthreads();
    int incl = v;
    for (int off = 1; off < 256; off <<= 1) {
        int y = (t >= off) ? lds[t - off] : 0;
        __syncthreads();
        incl += y;
        lds[t] = incl;
        __syncthreads();
    }
    if (t < nblk) blksum[t] = incl - v;
    if (t == nblk - 1) row_ptr[N_NODES] = incl;
}

__global__ void scan3_kernel(int* __restrict__ row_ptr, const int* __restrict__ blksum, int n) {
    int i = blockIdx.x * blockDim.x + threadIdx.x;
    if (i < n) row_ptr[i] += blksum[i >> 8];
}

__global__ void fill_kernel(const int* __restrict__ ei, const int* __restrict__ row_ptr,
                            int* __restrict__ fillc, int* __restrict__ csr_src) {
    int e = blockIdx.x * blockDim.x + threadIdx.x;
    if (e >= E_TOT) return;
    int src, dst;
    if (e < E_RAW) { src = ei[e]; dst = ei[E_RAW + e]; }
    else           { src = dst = e - E_RAW; }
    int slot = row_ptr[dst] + atomicAdd(&fillc[dst], 1);
    csr_src[slot] = src;
}

// ---------- GEMM + fused attention dots; H written as packed fp8 e4m3 ----------
// 64-row tiles (782 blocks) for better load balance across 256 CUs.
__global__ __launch_bounds__(256) void gemm_dots_kernel(
    const float* __restrict__ X, const float* __restrict__ W,
    const float* __restrict__ asrc, const float* __restrict__ adst,
    uint* __restrict__ Hb, float* __restrict__ s1, float* __restrict__ s2, int nrows) {
    __shared__ float Wl[DIM][DIM];
    int t = threadIdx.x;
    for (int i = t; i < DIM * DIM / 4; i += 256)
        ((float4*)&Wl[0][0])[i] = ((const float4*)W)[i];
    __syncthreads();

    int tx = t & 15, ty = t >> 4;
    int row0 = blockIdx.x * 64 + ty * 4;
    int col0 = tx * 8;
    float acc[4][8];
#pragma unroll
    for (int r = 0; r < 4; ++r)
#pragma unroll
        for (int c = 0; c < 8; ++c) acc[r][c] = 0.f;

    for (int k = 0; k < DIM; k += 4) {
        float4 xr[4];
#pragma unroll
        for (int r = 0; r < 4; ++r) {
            int row = row0 + r;
            xr[r] = (row < nrows) ? *(const float4*)&X[row * DIM + k]
                                  : make_float4(0.f, 0.f, 0.f, 0.f);
        }
#pragma unroll
        for (int kk = 0; kk < 4; ++kk) {
            float w0[8];
#pragma unroll
            for (int c = 0; c < 8; ++c) w0[c] = Wl[k + kk][col0 + c];
#pragma unroll
            for (int r = 0; r < 4; ++r) {
                float xv = (kk == 0) ? xr[r].x : (kk == 1) ? xr[r].y : (kk == 2) ? xr[r].z : xr[r].w;
#pragma unroll
                for (int c = 0; c < 8; ++c) acc[r][c] = fmaf(xv, w0[c], acc[r][c]);
            }
        }
    }

    float a1r[8], a2r[8];
#pragma unroll
    for (int c = 0; c < 8; ++c) { a1r[c] = asrc[col0 + c]; a2r[c] = adst[col0 + c]; }

#pragma unroll
    for (int r = 0; r < 4; ++r) {
        int row = row0 + r;
        if (row < nrows) {
            int w0 = __builtin_amdgcn_cvt_pk_fp8_f32(acc[r][0], acc[r][1], 0, false);
            w0     = __builtin_amdgcn_cvt_pk_fp8_f32(acc[r][2], acc[r][3], w0, true);
            int w1 = __builtin_amdgcn_cvt_pk_fp8_f32(acc[r][4], acc[r][5], 0, false);
            w1     = __builtin_amdgcn_cvt_pk_fp8_f32(acc[r][6], acc[r][7], w1, true);
            *(uint2*)&Hb[(size_t)row * 32 + tx * 2] = make_uint2((uint)w0, (uint)w1);
        }
        float p1 = 0.f, p2 = 0.f;
#pragma unroll
        for (int c = 0; c < 8; ++c) { p1 = fmaf(acc[r][c], a1r[c], p1); p2 = fmaf(acc[r][c], a2r[c], p2); }
#pragma unroll
        for (int m = 1; m < 16; m <<= 1) { p1 += __shfl_xor(p1, m); p2 += __shfl_xor(p2, m); }
        if (tx == 0 && row < nrows) { s1[row] = p1; s2[row] = p2; }
    }
}

// ---------- fused softmax + aggregation: one wave per dst node (R7 structure) ----------
// H rows fp8 (128 B, one contiguous segment per gather instruction — the fast
// path on gfx950; multi-segment gathers regress 1.7x, measured R5/R8).
// Segments padded to multiple of 4; second metadata quad masked if absent.
// Last layer writes only the pooled sums (Xout skipped).
__global__ __launch_bounds__(256) void agg_kernel(
    const ushort* __restrict__ Hb16, const int* __restrict__ csr_src,
    const int* __restrict__ row_ptr, const float* __restrict__ s1,
    const float* __restrict__ s2n, const float* __restrict__ bias,
    float2* __restrict__ Xout2, const int* __restrict__ batch,
    float* __restrict__ pooled, int pool_flag, int n) {
    int wid = (blockIdx.x * blockDim.x + threadIdx.x) >> 6;
    int lane = threadIdx.x & 63;
    if (wid >= n) return;
    int beg = row_ptr[wid], end = row_ptr[wid + 1];
    float s2v = s2n[wid];
    float2 acc = make_float2(0.f, 0.f);
    float wsum = 0.f;

    for (int s = beg; s < end; s += 8) {
        int4 a = *(const int4*)&csr_src[s];
        bool vb = (s + 4) < end;                     // wave-uniform
        int4 b = vb ? *(const int4*)&csr_src[s + 4] : make_int4(-1, -1, -1, -1);
        int sn[8] = {a.x, a.y, a.z, a.w, b.x, b.y, b.z, b.w};
        ushort hv[8];
#pragma unroll
        for (int j = 0; j < 8; ++j) {
            int r = (sn[j] < 0) ? 0 : sn[j];
            hv[j] = Hb16[(size_t)r * 64 + lane];
        }
        float w[8];
#pragma unroll
        for (int j = 0; j < 8; ++j) {
            int r = (sn[j] < 0) ? 0 : sn[j];
            float al = s1[r] + s2v;
            al = (al > 0.f) ? al : NEG_SLOPE * al;
            float e = __expf(al);
            w[j] = (sn[j] < 0) ? 0.f : e;
            wsum += w[j];
        }
#pragma unroll
        for (int j = 0; j < 8; ++j) {
            v2f f = __builtin_amdgcn_cvt_pk_f32_fp8((int)hv[j], false);
            acc.x = fmaf(w[j], f.x, acc.x);
            acc.y = fmaf(w[j], f.y, acc.y);
        }
    }

    float inv = 1.f / (wsum + 1e-16f);
    float2 b2 = ((const float2*)bias)[lane];
    acc.x = fmaxf(fmaf(acc.x, inv, b2.x), 0.f);
    acc.y = fmaxf(fmaf(acc.y, inv, b2.y), 0.f);
    if (pool_flag) {
        int g = batch[wid];
        atomicAdd(&pooled[g * DIM + 2 * lane], acc.x);
        atomicAdd(&pooled[g * DIM + 2 * lane + 1], acc.y);
    } else {
        Xout2[(size_t)wid * 64 + lane] = acc;
    }
}

__global__ void final_kernel(const float* __restrict__ pooled, const float* __restrict__ Wf,
                             const float* __restrict__ bf, float* __restrict__ y) {
    int wid = (blockIdx.x * blockDim.x + threadIdx.x) >> 6;
    int lane = threadIdx.x & 63;
    if (wid >= N_GRAPHS) return;
    float2 p = *(const float2*)&pooled[wid * DIM + 2 * lane];
    float2 w = *(const float2*)&Wf[2 * lane];
    float v = p.x * w.x + p.y * w.y;
    for (int off = 32; off; off >>= 1) v += __shfl_down(v, off);
    if (lane == 0) y[wid] = v + bf[0];
}

extern "C" void kernel_launch(void* const* d_in, const int* in_sizes, int n_in,
                              void* d_out, int out_size, void* d_ws, size_t ws_size,
                              hipStream_t stream) {
    const float* x       = (const float*)d_in[0];
    const int*   ei      = (const int*)d_in[1];
    const int*   batch   = (const int*)d_in[2];
    const float* Ws      = (const float*)d_in[3];
    const float* att_src = (const float*)d_in[4];
    const float* att_dst = (const float*)d_in[5];
    const float* biases  = (const float*)d_in[6];
    const float* Wf      = (const float*)d_in[7];
    const float* bf      = (const float*)d_in[8];
    float* y = (float*)d_out;

    char* p = (char*)d_ws;
    auto alloc = [&](size_t bytes) -> void* {
        void* r = (void*)p;
        p += (bytes + 255) & ~(size_t)255;
        return r;
    };
    float* xA      = (float*)alloc((size_t)N_NODES * DIM * 4);
    float* xB      = (float*)alloc((size_t)N_NODES * DIM * 4);
    uint*  Hb      = (uint*)alloc((size_t)N_NODES * 32 * 4);   // fp8 e4m3, 128 B/row
    int*   csr_src = (int*)alloc((size_t)E_CAP * 4);
    int*   deg     = (int*)alloc((size_t)N_NODES * 4);
    int*   fillc   = (int*)alloc((size_t)N_NODES * 4);
    int*   row_ptr = (int*)alloc((size_t)(N_NODES + 1) * 4);
    int*   blksum  = (int*)alloc(256 * 4);
    float* s1      = (float*)alloc((size_t)N_NODES * 4);
    float* s2      = (float*)alloc((size_t)N_NODES * 4);
    float* pooled  = (float*)alloc((size_t)N_GRAPHS * DIM * 4);

    const int BN = 256;
    const int gN   = (N_NODES + BN - 1) / BN;
    const int gE   = (E_TOT + BN - 1) / BN;
    const int gI   = (E_CAP + BN - 1) / BN;
    const int gNW  = (N_NODES * 64 + BN - 1) / BN;  // one wave per node
    const int nblk = gN;

    init_kernel<<<gI, BN, 0, stream>>>(deg, fillc, pooled, csr_src);
    count_kernel<<<gE, BN, 0, stream>>>(ei, deg);
    scan1_kernel<<<nblk, BN, 0, stream>>>(deg, row_ptr, blksum, N_NODES);
    scan2_kernel<<<1, BN, 0, stream>>>(blksum, row_ptr, nblk);
    scan3_kernel<<<gN, BN, 0, stream>>>(row_ptr, blksum, N_NODES);
    fill_kernel<<<gE, BN, 0, stream>>>(ei, row_ptr, fillc, csr_src);

    const float* xin = x;
    float* xout = xA;
    for (int l = 0; l < 3; ++l) {
        const float* W  = Ws + (size_t)l * DIM * DIM;
        const float* as = att_src + (size_t)l * DIM;
        const float* ad = att_dst + (size_t)l * DIM;
        const float* b  = biases + (size_t)l * DIM;

        gemm_dots_kernel<<<(N_NODES + 63) / 64, BN, 0, stream>>>(xin, W, as, ad, Hb, s1, s2, N_NODES);
        agg_kernel<<<gNW, BN, 0, stream>>>((const ushort*)Hb, csr_src, row_ptr, s1, s2, b,
                                           (float2*)xout, batch, pooled,
                                           (l == 2) ? 1 : 0, N_NODES);
        xin = xout;
        xout = (l == 0) ? xB : xA;
    }

    final_kernel<<<(N_GRAPHS * 64 + BN - 1) / BN, BN, 0, stream>>>(pooled, Wf, bf, y);
    (void)ws_size; (void)n_in; (void)in_sizes; (void)out_size;
}

// Round 10
// 522.917 us; speedup vs baseline: 1.2090x; 1.0836x over previous
//
#include <hip/hip_runtime.h>
#include <hip/hip_bf16.h>

#define N_NODES 50000
#define DIM 128
#define N_GRAPHS 64
#define E_RAW 800000
#define E_TOT 850000
#define E_CAP 1200000   // >= E_TOT + 3*N_NODES (pad-to-4) + slack
#define NEG_SLOPE 0.2f

typedef unsigned int uint;
typedef unsigned short ushort;
typedef float v2f __attribute__((ext_vector_type(2)));

// ---------- init: counters + pooled only (csr pads written by pad_kernel) ----------
__global__ void init_kernel(int* deg, int* fillc, float* pooled) {
    int i = blockIdx.x * blockDim.x + threadIdx.x;
    if (i < N_NODES) { deg[i] = 0; fillc[i] = 0; }
    if (i < N_GRAPHS * DIM) pooled[i] = 0.f;
}

// ---------- CSR build (dst-sorted, segments padded to multiple of 4) ----------
__global__ void count_kernel(const int* __restrict__ ei, int* __restrict__ deg) {
    int e = blockIdx.x * blockDim.x + threadIdx.x;
    if (e >= E_TOT) return;
    int dst = (e < E_RAW) ? ei[E_RAW + e] : (e - E_RAW);
    atomicAdd(&deg[dst], 1);
}

__global__ void scan1_kernel(const int* __restrict__ deg, int* __restrict__ excl,
                             int* __restrict__ blksum, int n) {
    __shared__ int lds[256];
    int t = threadIdx.x;
    int i = blockIdx.x * 256 + t;
    int v = (i < n) ? ((deg[i] + 3) & ~3) : 0;   // pad degree to multiple of 4
    lds[t] = v;
    __syncthreads();
    int incl = v;
    for (int off = 1; off < 256; off <<= 1) {
        int y = (t >= off) ? lds[t - off] : 0;
        __syncthreads();
        incl += y;
        lds[t] = incl;
        __syncthreads();
    }
    if (i < n) excl[i] = incl - v;
    if (t == 255) blksum[blockIdx.x] = incl;
}

__global__ void scan2_kernel(int* __restrict__ blksum, int* __restrict__ row_ptr, int nblk) {
    __shared__ int lds[256];
    int t = threadIdx.x;
    int v = (t < nblk) ? blksum[t] : 0;
    lds[t] = v;
    __syncthreads();
    int incl = v;
    for (int off = 1; off < 256; off <<= 1) {
        int y = (t >= off) ? lds[t - off] : 0;
        __syncthreads();
        incl += y;
        lds[t] = incl;
        __syncthreads();
    }
    if (t < nblk) blksum[t] = incl - v;
    if (t == nblk - 1) row_ptr[N_NODES] = incl;
}

__global__ void scan3_kernel(int* __restrict__ row_ptr, const int* __restrict__ blksum, int n) {
    int i = blockIdx.x * blockDim.x + threadIdx.x;
    if (i < n) row_ptr[i] += blksum[i >> 8];
}

// write -1 into the <=3 pad slots of each node's segment
__global__ void pad_kernel(const int* __restrict__ deg, const int* __restrict__ row_ptr,
                           int* __restrict__ csr_src) {
    int i = blockIdx.x * blockDim.x + threadIdx.x;
    if (i >= N_NODES) return;
    int d = deg[i];
    int pd = (d + 3) & ~3;
    int base = row_ptr[i];
    for (int k = d; k < pd; ++k) csr_src[base + k] = -1;
}

__global__ void fill_kernel(const int* __restrict__ ei, const int* __restrict__ row_ptr,
                            int* __restrict__ fillc, int* __restrict__ csr_src) {
    int e = blockIdx.x * blockDim.x + threadIdx.x;
    if (e >= E_TOT) return;
    int src, dst;
    if (e < E_RAW) { src = ei[e]; dst = ei[E_RAW + e]; }
    else           { src = dst = e - E_RAW; }
    int slot = row_ptr[dst] + atomicAdd(&fillc[dst], 1);
    csr_src[slot] = src;
}

// ---------- GEMM + fused attention dots; H written as packed fp8 e4m3 ----------
__global__ __launch_bounds__(256) void gemm_dots_kernel(
    const float* __restrict__ X, const float* __restrict__ W,
    const float* __restrict__ asrc, const float* __restrict__ adst,
    uint* __restrict__ Hb, float* __restrict__ s1, float* __restrict__ s2, int nrows) {
    __shared__ float Wl[DIM][DIM];
    int t = threadIdx.x;
    for (int i = t; i < DIM * DIM / 4; i += 256)
        ((float4*)&Wl[0][0])[i] = ((const float4*)W)[i];
    __syncthreads();

    int tx = t & 15, ty = t >> 4;
    int row0 = blockIdx.x * 64 + ty * 4;
    int col0 = tx * 8;
    float acc[4][8];
#pragma unroll
    for (int r = 0; r < 4; ++r)
#pragma unroll
        for (int c = 0; c < 8; ++c) acc[r][c] = 0.f;

    for (int k = 0; k < DIM; k += 4) {
        float4 xr[4];
#pragma unroll
        for (int r = 0; r < 4; ++r) {
            int row = row0 + r;
            xr[r] = (row < nrows) ? *(const float4*)&X[row * DIM + k]
                                  : make_float4(0.f, 0.f, 0.f, 0.f);
        }
#pragma unroll
        for (int kk = 0; kk < 4; ++kk) {
            float w0[8];
#pragma unroll
            for (int c = 0; c < 8; ++c) w0[c] = Wl[k + kk][col0 + c];
#pragma unroll
            for (int r = 0; r < 4; ++r) {
                float xv = (kk == 0) ? xr[r].x : (kk == 1) ? xr[r].y : (kk == 2) ? xr[r].z : xr[r].w;
#pragma unroll
                for (int c = 0; c < 8; ++c) acc[r][c] = fmaf(xv, w0[c], acc[r][c]);
            }
        }
    }

    float a1r[8], a2r[8];
#pragma unroll
    for (int c = 0; c < 8; ++c) { a1r[c] = asrc[col0 + c]; a2r[c] = adst[col0 + c]; }

#pragma unroll
    for (int r = 0; r < 4; ++r) {
        int row = row0 + r;
        if (row < nrows) {
            int w0 = __builtin_amdgcn_cvt_pk_fp8_f32(acc[r][0], acc[r][1], 0, false);
            w0     = __builtin_amdgcn_cvt_pk_fp8_f32(acc[r][2], acc[r][3], w0, true);
            int w1 = __builtin_amdgcn_cvt_pk_fp8_f32(acc[r][4], acc[r][5], 0, false);
            w1     = __builtin_amdgcn_cvt_pk_fp8_f32(acc[r][6], acc[r][7], w1, true);
            *(uint2*)&Hb[(size_t)row * 32 + tx * 2] = make_uint2((uint)w0, (uint)w1);
        }
        float p1 = 0.f, p2 = 0.f;
#pragma unroll
        for (int c = 0; c < 8; ++c) { p1 = fmaf(acc[r][c], a1r[c], p1); p2 = fmaf(acc[r][c], a2r[c], p2); }
#pragma unroll
        for (int m = 1; m < 16; m <<= 1) { p1 += __shfl_xor(p1, m); p2 += __shfl_xor(p2, m); }
        if (tx == 0 && row < nrows) { s1[row] = p1; s2[row] = p2; }
    }
}

// ---------- fused softmax + aggregation: one wave per FOUR dst nodes ----------
// Head loads (row_ptr int4+1, s2 float4, batch int4) amortized over 4 nodes;
// their CSR ranges are contiguous so metadata streams. Inner loop identical to
// R9: one contiguous 128 B fp8 row per gather instruction (the only shape that
// doesn't regress on gfx950 — R5/R8 multi-segment gathers were 1.7x slower).
__global__ __launch_bounds__(256) void agg_kernel(
    const ushort* __restrict__ Hb16, const int* __restrict__ csr_src,
    const int* __restrict__ row_ptr, const float* __restrict__ s1,
    const float* __restrict__ s2n, const float* __restrict__ bias,
    float2* __restrict__ Xout2, const int* __restrict__ batch,
    float* __restrict__ pooled, int pool_flag, int ngroups) {
    int gw = (blockIdx.x * blockDim.x + threadIdx.x) >> 6;
    int lane = threadIdx.x & 63;
    if (gw >= ngroups) return;
    int node0 = gw * 4;

    int4 rp0 = *(const int4*)&row_ptr[node0];   // row_ptr[node0..node0+3]
    int rp4 = row_ptr[node0 + 4];
    int rp[5] = {rp0.x, rp0.y, rp0.z, rp0.w, rp4};
    float4 s2q = *(const float4*)&s2n[node0];
    float s2a[4] = {s2q.x, s2q.y, s2q.z, s2q.w};
    float2 b2 = ((const float2*)bias)[lane];
    int4 bq = make_int4(0, 0, 0, 0);
    if (pool_flag) bq = *(const int4*)&batch[node0];
    int ba[4] = {bq.x, bq.y, bq.z, bq.w};

#pragma unroll
    for (int k = 0; k < 4; ++k) {
        int beg = rp[k], end = rp[k + 1];
        float s2v = s2a[k];
        float2 acc = make_float2(0.f, 0.f);
        float wsum = 0.f;

        for (int s = beg; s < end; s += 8) {
            int4 a = *(const int4*)&csr_src[s];
            bool vb = (s + 4) < end;                     // wave-uniform
            int4 b = vb ? *(const int4*)&csr_src[s + 4] : make_int4(-1, -1, -1, -1);
            int sn[8] = {a.x, a.y, a.z, a.w, b.x, b.y, b.z, b.w};
            ushort hv[8];
#pragma unroll
            for (int j = 0; j < 8; ++j) {
                int r = (sn[j] < 0) ? 0 : sn[j];
                hv[j] = Hb16[(size_t)r * 64 + lane];
            }
            float w[8];
#pragma unroll
            for (int j = 0; j < 8; ++j) {
                int r = (sn[j] < 0) ? 0 : sn[j];
                float al = s1[r] + s2v;
                al = (al > 0.f) ? al : NEG_SLOPE * al;
                float e = __expf(al);
                w[j] = (sn[j] < 0) ? 0.f : e;
                wsum += w[j];
            }
#pragma unroll
            for (int j = 0; j < 8; ++j) {
                v2f f = __builtin_amdgcn_cvt_pk_f32_fp8((int)hv[j], false);
                acc.x = fmaf(w[j], f.x, acc.x);
                acc.y = fmaf(w[j], f.y, acc.y);
            }
        }

        float inv = 1.f / (wsum + 1e-16f);
        acc.x = fmaxf(fmaf(acc.x, inv, b2.x), 0.f);
        acc.y = fmaxf(fmaf(acc.y, inv, b2.y), 0.f);
        if (pool_flag) {
            atomicAdd(&pooled[ba[k] * DIM + 2 * lane], acc.x);
            atomicAdd(&pooled[ba[k] * DIM + 2 * lane + 1], acc.y);
        } else {
            Xout2[(size_t)(node0 + k) * 64 + lane] = acc;
        }
    }
}

__global__ void final_kernel(const float* __restrict__ pooled, const float* __restrict__ Wf,
                             const float* __restrict__ bf, float* __restrict__ y) {
    int wid = (blockIdx.x * blockDim.x + threadIdx.x) >> 6;
    int lane = threadIdx.x & 63;
    if (wid >= N_GRAPHS) return;
    float2 p = *(const float2*)&pooled[wid * DIM + 2 * lane];
    float2 w = *(const float2*)&Wf[2 * lane];
    float v = p.x * w.x + p.y * w.y;
    for (int off = 32; off; off >>= 1) v += __shfl_down(v, off);
    if (lane == 0) y[wid] = v + bf[0];
}

extern "C" void kernel_launch(void* const* d_in, const int* in_sizes, int n_in,
                              void* d_out, int out_size, void* d_ws, size_t ws_size,
                              hipStream_t stream) {
    const float* x       = (const float*)d_in[0];
    const int*   ei      = (const int*)d_in[1];
    const int*   batch   = (const int*)d_in[2];
    const float* Ws      = (const float*)d_in[3];
    const float* att_src = (const float*)d_in[4];
    const float* att_dst = (const float*)d_in[5];
    const float* biases  = (const float*)d_in[6];
    const float* Wf      = (const float*)d_in[7];
    const float* bf      = (const float*)d_in[8];
    float* y = (float*)d_out;

    char* p = (char*)d_ws;
    auto alloc = [&](size_t bytes) -> void* {
        void* r = (void*)p;
        p += (bytes + 255) & ~(size_t)255;
        return r;
    };
    float* xA      = (float*)alloc((size_t)N_NODES * DIM * 4);
    float* xB      = (float*)alloc((size_t)N_NODES * DIM * 4);
    uint*  Hb      = (uint*)alloc((size_t)N_NODES * 32 * 4);   // fp8 e4m3, 128 B/row
    int*   csr_src = (int*)alloc((size_t)E_CAP * 4);
    int*   deg     = (int*)alloc((size_t)N_NODES * 4);
    int*   fillc   = (int*)alloc((size_t)N_NODES * 4);
    int*   row_ptr = (int*)alloc((size_t)(N_NODES + 8) * 4);
    int*   blksum  = (int*)alloc(256 * 4);
    float* s1      = (float*)alloc((size_t)N_NODES * 4);
    float* s2      = (float*)alloc((size_t)(N_NODES + 4) * 4);
    float* pooled  = (float*)alloc((size_t)N_GRAPHS * DIM * 4);

    const int BN = 256;
    const int gN   = (N_NODES + BN - 1) / BN;
    const int gE   = (E_TOT + BN - 1) / BN;
    const int ngroups = N_NODES / 4;                 // 12500, exact
    const int gAGG = (ngroups * 64 + BN - 1) / BN;   // one wave per 4 nodes
    const int nblk = gN;

    init_kernel<<<gN, BN, 0, stream>>>(deg, fillc, pooled);
    count_kernel<<<gE, BN, 0, stream>>>(ei, deg);
    scan1_kernel<<<nblk, BN, 0, stream>>>(deg, row_ptr, blksum, N_NODES);
    scan2_kernel<<<1, BN, 0, stream>>>(blksum, row_ptr, nblk);
    scan3_kernel<<<gN, BN, 0, stream>>>(row_ptr, blksum, N_NODES);
    pad_kernel<<<gN, BN, 0, stream>>>(deg, row_ptr, csr_src);
    fill_kernel<<<gE, BN, 0, stream>>>(ei, row_ptr, fillc, csr_src);

    const float* xin = x;
    float* xout = xA;
    for (int l = 0; l < 3; ++l) {
        const float* W  = Ws + (size_t)l * DIM * DIM;
        const float* as = att_src + (size_t)l * DIM;
        const float* ad = att_dst + (size_t)l * DIM;
        const float* b  = biases + (size_t)l * DIM;

        gemm_dots_kernel<<<(N_NODES + 63) / 64, BN, 0, stream>>>(xin, W, as, ad, Hb, s1, s2, N_NODES);
        agg_kernel<<<gAGG, BN, 0, stream>>>((const ushort*)Hb, csr_src, row_ptr, s1, s2, b,
                                            (float2*)xout, batch, pooled,
                                            (l == 2) ? 1 : 0, ngroups);
        xin = xout;
        xout = (l == 0) ? xB : xA;
    }

    final_kernel<<<(N_GRAPHS * 64 + BN - 1) / BN, BN, 0, stream>>>(pooled, Wf, bf, y);
    (void)ws_size; (void)n_in; (void)in_sizes; (void)out_size;
}

// Round 11
// 509.976 us; speedup vs baseline: 1.2397x; 1.0254x over previous
//
#include <hip/hip_runtime.h>
#include <hip/hip_bf16.h>

#define N_NODES 50000
#define DIM 128
#define N_GRAPHS 64
#define E_RAW 800000
#define E_TOT 850000
#define E_CAP 1200000   // >= E_TOT + 3*N_NODES (pad-to-4) + slack
#define NEG_SLOPE 0.2f

typedef unsigned int uint;
typedef unsigned short ushort;
typedef float v2f __attribute__((ext_vector_type(2)));

// ---------- init: counters + pooled only ----------
__global__ void init_kernel(int* deg, int* fillc, float* pooled) {
    int i = blockIdx.x * blockDim.x + threadIdx.x;
    if (i < N_NODES) { deg[i] = 0; fillc[i] = 0; }
    if (i < N_GRAPHS * DIM) pooled[i] = 0.f;
}

// ---------- CSR build (dst-sorted, segments padded to multiple of 4) ----------
__global__ void count_kernel(const int* __restrict__ ei, int* __restrict__ deg) {
    int e = blockIdx.x * blockDim.x + threadIdx.x;
    if (e >= E_TOT) return;
    int dst = (e < E_RAW) ? ei[E_RAW + e] : (e - E_RAW);
    atomicAdd(&deg[dst], 1);
}

__global__ void scan1_kernel(const int* __restrict__ deg, int* __restrict__ excl,
                             int* __restrict__ blksum, int n) {
    __shared__ int lds[256];
    int t = threadIdx.x;
    int i = blockIdx.x * 256 + t;
    int v = (i < n) ? ((deg[i] + 3) & ~3) : 0;   // pad degree to multiple of 4
    lds[t] = v;
    __syncthreads();
    int incl = v;
    for (int off = 1; off < 256; off <<= 1) {
        int y = (t >= off) ? lds[t - off] : 0;
        __syncthreads();
        incl += y;
        lds[t] = incl;
        __syncthreads();
    }
    if (i < n) excl[i] = incl - v;
    if (t == 255) blksum[blockIdx.x] = incl;
}

__global__ void scan2_kernel(int* __restrict__ blksum, int* __restrict__ row_ptr, int nblk) {
    __shared__ int lds[256];
    int t = threadIdx.x;
    int v = (t < nblk) ? blksum[t] : 0;
    lds[t] = v;
    __syncthreads();
    int incl = v;
    for (int off = 1; off < 256; off <<= 1) {
        int y = (t >= off) ? lds[t - off] : 0;
        __syncthreads();
        incl += y;
        lds[t] = incl;
        __syncthreads();
    }
    if (t < nblk) blksum[t] = incl - v;
    if (t == nblk - 1) row_ptr[N_NODES] = incl;
}

__global__ void scan3_kernel(int* __restrict__ row_ptr, const int* __restrict__ blksum, int n) {
    int i = blockIdx.x * blockDim.x + threadIdx.x;
    if (i < n) row_ptr[i] += blksum[i >> 8];
}

// write -1 into the <=3 pad slots of each node's segment
__global__ void pad_kernel(const int* __restrict__ deg, const int* __restrict__ row_ptr,
                           int* __restrict__ csr_src) {
    int i = blockIdx.x * blockDim.x + threadIdx.x;
    if (i >= N_NODES) return;
    int d = deg[i];
    int pd = (d + 3) & ~3;
    int base = row_ptr[i];
    for (int k = d; k < pd; ++k) csr_src[base + k] = -1;
}

__global__ void fill_kernel(const int* __restrict__ ei, const int* __restrict__ row_ptr,
                            int* __restrict__ fillc, int* __restrict__ csr_src) {
    int e = blockIdx.x * blockDim.x + threadIdx.x;
    if (e >= E_TOT) return;
    int src, dst;
    if (e < E_RAW) { src = ei[e]; dst = ei[E_RAW + e]; }
    else           { src = dst = e - E_RAW; }
    int slot = row_ptr[dst] + atomicAdd(&fillc[dst], 1);
    csr_src[slot] = src;
}

// ---------- GEMM + fused attention dots; H written as packed fp8 e4m3 ----------
__global__ __launch_bounds__(256) void gemm_dots_kernel(
    const float* __restrict__ X, const float* __restrict__ W,
    const float* __restrict__ asrc, const float* __restrict__ adst,
    uint* __restrict__ Hb, float* __restrict__ s1, float* __restrict__ s2, int nrows) {
    __shared__ float Wl[DIM][DIM];
    int t = threadIdx.x;
    for (int i = t; i < DIM * DIM / 4; i += 256)
        ((float4*)&Wl[0][0])[i] = ((const float4*)W)[i];
    __syncthreads();

    int tx = t & 15, ty = t >> 4;
    int row0 = blockIdx.x * 64 + ty * 4;
    int col0 = tx * 8;
    float acc[4][8];
#pragma unroll
    for (int r = 0; r < 4; ++r)
#pragma unroll
        for (int c = 0; c < 8; ++c) acc[r][c] = 0.f;

    for (int k = 0; k < DIM; k += 4) {
        float4 xr[4];
#pragma unroll
        for (int r = 0; r < 4; ++r) {
            int row = row0 + r;
            xr[r] = (row < nrows) ? *(const float4*)&X[row * DIM + k]
                                  : make_float4(0.f, 0.f, 0.f, 0.f);
        }
#pragma unroll
        for (int kk = 0; kk < 4; ++kk) {
            float w0[8];
#pragma unroll
            for (int c = 0; c < 8; ++c) w0[c] = Wl[k + kk][col0 + c];
#pragma unroll
            for (int r = 0; r < 4; ++r) {
                float xv = (kk == 0) ? xr[r].x : (kk == 1) ? xr[r].y : (kk == 2) ? xr[r].z : xr[r].w;
#pragma unroll
                for (int c = 0; c < 8; ++c) acc[r][c] = fmaf(xv, w0[c], acc[r][c]);
            }
        }
    }

    float a1r[8], a2r[8];
#pragma unroll
    for (int c = 0; c < 8; ++c) { a1r[c] = asrc[col0 + c]; a2r[c] = adst[col0 + c]; }

#pragma unroll
    for (int r = 0; r < 4; ++r) {
        int row = row0 + r;
        if (row < nrows) {
            int w0 = __builtin_amdgcn_cvt_pk_fp8_f32(acc[r][0], acc[r][1], 0, false);
            w0     = __builtin_amdgcn_cvt_pk_fp8_f32(acc[r][2], acc[r][3], w0, true);
            int w1 = __builtin_amdgcn_cvt_pk_fp8_f32(acc[r][4], acc[r][5], 0, false);
            w1     = __builtin_amdgcn_cvt_pk_fp8_f32(acc[r][6], acc[r][7], w1, true);
            *(uint2*)&Hb[(size_t)row * 32 + tx * 2] = make_uint2((uint)w0, (uint)w1);
        }
        float p1 = 0.f, p2 = 0.f;
#pragma unroll
        for (int c = 0; c < 8; ++c) { p1 = fmaf(acc[r][c], a1r[c], p1); p2 = fmaf(acc[r][c], a2r[c], p2); }
#pragma unroll
        for (int m = 1; m < 16; m <<= 1) { p1 += __shfl_xor(p1, m); p2 += __shfl_xor(p2, m); }
        if (tx == 0 && row < nrows) { s1[row] = p1; s2[row] = p2; }
    }
}

// ---------- fused softmax + aggregation: one wave per EIGHT dst nodes ----------
// Head loads (row_ptr 2xint4+1, s2 2xfloat4, batch 2xint4) amortized over ~136
// edges. Inner loop identical to R9/R10: one contiguous 128 B fp8 row per
// gather instruction (multi-segment gathers regress 1.7x — measured R5/R8).
__global__ __launch_bounds__(256) void agg_kernel(
    const ushort* __restrict__ Hb16, const int* __restrict__ csr_src,
    const int* __restrict__ row_ptr, const float* __restrict__ s1,
    const float* __restrict__ s2n, const float* __restrict__ bias,
    float2* __restrict__ Xout2, const int* __restrict__ batch,
    float* __restrict__ pooled, int pool_flag, int ngroups) {
    int gw = (blockIdx.x * blockDim.x + threadIdx.x) >> 6;
    int lane = threadIdx.x & 63;
    if (gw >= ngroups) return;
    int node0 = gw * 8;

    int4 rpa = *(const int4*)&row_ptr[node0];
    int4 rpb = *(const int4*)&row_ptr[node0 + 4];
    int rp8 = row_ptr[node0 + 8];
    int rp[9] = {rpa.x, rpa.y, rpa.z, rpa.w, rpb.x, rpb.y, rpb.z, rpb.w, rp8};
    float4 s2qa = *(const float4*)&s2n[node0];
    float4 s2qb = *(const float4*)&s2n[node0 + 4];
    float s2a[8] = {s2qa.x, s2qa.y, s2qa.z, s2qa.w, s2qb.x, s2qb.y, s2qb.z, s2qb.w};
    float2 b2 = ((const float2*)bias)[lane];
    int ba[8] = {0, 0, 0, 0, 0, 0, 0, 0};
    if (pool_flag) {
        int4 bqa = *(const int4*)&batch[node0];
        int4 bqb = *(const int4*)&batch[node0 + 4];
        ba[0] = bqa.x; ba[1] = bqa.y; ba[2] = bqa.z; ba[3] = bqa.w;
        ba[4] = bqb.x; ba[5] = bqb.y; ba[6] = bqb.z; ba[7] = bqb.w;
    }

#pragma unroll
    for (int k = 0; k < 8; ++k) {
        int beg = rp[k], end = rp[k + 1];
        float s2v = s2a[k];
        float2 acc = make_float2(0.f, 0.f);
        float wsum = 0.f;

        for (int s = beg; s < end; s += 8) {
            int4 a = *(const int4*)&csr_src[s];
            bool vb = (s + 4) < end;                     // wave-uniform
            int4 b = vb ? *(const int4*)&csr_src[s + 4] : make_int4(-1, -1, -1, -1);
            int sn[8] = {a.x, a.y, a.z, a.w, b.x, b.y, b.z, b.w};
            ushort hv[8];
#pragma unroll
            for (int j = 0; j < 8; ++j) {
                int r = (sn[j] < 0) ? 0 : sn[j];
                hv[j] = Hb16[(size_t)r * 64 + lane];
            }
            float w[8];
#pragma unroll
            for (int j = 0; j < 8; ++j) {
                int r = (sn[j] < 0) ? 0 : sn[j];
                float al = s1[r] + s2v;
                al = (al > 0.f) ? al : NEG_SLOPE * al;
                float e = __expf(al);
                w[j] = (sn[j] < 0) ? 0.f : e;
                wsum += w[j];
            }
#pragma unroll
            for (int j = 0; j < 8; ++j) {
                v2f f = __builtin_amdgcn_cvt_pk_f32_fp8((int)hv[j], false);
                acc.x = fmaf(w[j], f.x, acc.x);
                acc.y = fmaf(w[j], f.y, acc.y);
            }
        }

        float inv = 1.f / (wsum + 1e-16f);
        acc.x = fmaxf(fmaf(acc.x, inv, b2.x), 0.f);
        acc.y = fmaxf(fmaf(acc.y, inv, b2.y), 0.f);
        if (pool_flag) {
            atomicAdd(&pooled[ba[k] * DIM + 2 * lane], acc.x);
            atomicAdd(&pooled[ba[k] * DIM + 2 * lane + 1], acc.y);
        } else {
            Xout2[(size_t)(node0 + k) * 64 + lane] = acc;
        }
    }
}

__global__ void final_kernel(const float* __restrict__ pooled, const float* __restrict__ Wf,
                             const float* __restrict__ bf, float* __restrict__ y) {
    int wid = (blockIdx.x * blockDim.x + threadIdx.x) >> 6;
    int lane = threadIdx.x & 63;
    if (wid >= N_GRAPHS) return;
    float2 p = *(const float2*)&pooled[wid * DIM + 2 * lane];
    float2 w = *(const float2*)&Wf[2 * lane];
    float v = p.x * w.x + p.y * w.y;
    for (int off = 32; off; off >>= 1) v += __shfl_down(v, off);
    if (lane == 0) y[wid] = v + bf[0];
}

extern "C" void kernel_launch(void* const* d_in, const int* in_sizes, int n_in,
                              void* d_out, int out_size, void* d_ws, size_t ws_size,
                              hipStream_t stream) {
    const float* x       = (const float*)d_in[0];
    const int*   ei      = (const int*)d_in[1];
    const int*   batch   = (const int*)d_in[2];
    const float* Ws      = (const float*)d_in[3];
    const float* att_src = (const float*)d_in[4];
    const float* att_dst = (const float*)d_in[5];
    const float* biases  = (const float*)d_in[6];
    const float* Wf      = (const float*)d_in[7];
    const float* bf      = (const float*)d_in[8];
    float* y = (float*)d_out;

    char* p = (char*)d_ws;
    auto alloc = [&](size_t bytes) -> void* {
        void* r = (void*)p;
        p += (bytes + 255) & ~(size_t)255;
        return r;
    };
    float* xA      = (float*)alloc((size_t)N_NODES * DIM * 4);
    float* xB      = (float*)alloc((size_t)N_NODES * DIM * 4);
    uint*  Hb      = (uint*)alloc((size_t)N_NODES * 32 * 4);   // fp8 e4m3, 128 B/row
    int*   csr_src = (int*)alloc((size_t)E_CAP * 4);
    int*   deg     = (int*)alloc((size_t)N_NODES * 4);
    int*   fillc   = (int*)alloc((size_t)N_NODES * 4);
    int*   row_ptr = (int*)alloc((size_t)(N_NODES + 16) * 4);
    int*   blksum  = (int*)alloc(256 * 4);
    float* s1      = (float*)alloc((size_t)N_NODES * 4);
    float* s2      = (float*)alloc((size_t)(N_NODES + 8) * 4);
    float* pooled  = (float*)alloc((size_t)N_GRAPHS * DIM * 4);

    const int BN = 256;
    const int gN   = (N_NODES + BN - 1) / BN;
    const int gE   = (E_TOT + BN - 1) / BN;
    const int ngroups = N_NODES / 8;                 // 6250, exact
    const int gAGG = (ngroups * 64 + BN - 1) / BN;   // one wave per 8 nodes
    const int nblk = gN;

    init_kernel<<<gN, BN, 0, stream>>>(deg, fillc, pooled);
    count_kernel<<<gE, BN, 0, stream>>>(ei, deg);
    scan1_kernel<<<nblk, BN, 0, stream>>>(deg, row_ptr, blksum, N_NODES);
    scan2_kernel<<<1, BN, 0, stream>>>(blksum, row_ptr, nblk);
    scan3_kernel<<<gN, BN, 0, stream>>>(row_ptr, blksum, N_NODES);
    pad_kernel<<<gN, BN, 0, stream>>>(deg, row_ptr, csr_src);
    fill_kernel<<<gE, BN, 0, stream>>>(ei, row_ptr, fillc, csr_src);

    const float* xin = x;
    float* xout = xA;
    for (int l = 0; l < 3; ++l) {
        const float* W  = Ws + (size_t)l * DIM * DIM;
        const float* as = att_src + (size_t)l * DIM;
        const float* ad = att_dst + (size_t)l * DIM;
        const float* b  = biases + (size_t)l * DIM;

        gemm_dots_kernel<<<(N_NODES + 63) / 64, BN, 0, stream>>>(xin, W, as, ad, Hb, s1, s2, N_NODES);
        agg_kernel<<<gAGG, BN, 0, stream>>>((const ushort*)Hb, csr_src, row_ptr, s1, s2, b,
                                            (float2*)xout, batch, pooled,
                                            (l == 2) ? 1 : 0, ngroups);
        xin = xout;
        xout = (l == 0) ? xB : xA;
    }

    final_kernel<<<(N_GRAPHS * 64 + BN - 1) / BN, BN, 0, stream>>>(pooled, Wf, bf, y);
    (void)ws_size; (void)n_in; (void)in_sizes; (void)out_size;
}